// Round 3
// baseline (98.460 us; speedup 1.0000x reference)
//
#include <hip/hip_runtime.h>
#include <cstdint>

typedef __bf16 bf16x8 __attribute__((ext_vector_type(8)));
typedef float floatx4 __attribute__((ext_vector_type(4)));

// M = 4096 rows, C(K) = 256. GEMM block tile 128x128, K-slab 64.
//
// Staged global layout (produced by transpose_stage, consumed by GEMM):
//   Xs[rb(32)][s(4)][kk(2)][rowhi(8)][quad(4)][rowlo(16)][8 bf16]
// holding element X[row = rb*128+rowhi*16+rowlo][k = s*64+kk*32+quad*8+j].
// This is exactly the LDS image for conflict-free lane-linear ds_read_b128
// fragment reads AND lane-linear global_load_lds staging.

#define OFF_X     (0u)
#define OFF_Y     (2u*1024*1024)
#define OFF_PMAX  (4u*1024*1024)   // [g(64)][row(4096)] transposed partials
#define OFF_PSUM  (5u*1024*1024)
#define OFF_DIAG  (6u*1024*1024)

#define AS1C(p) ((const __attribute__((address_space(1))) void*)(const void*)(p))
#define AS3(p)  ((__attribute__((address_space(3))) void*)(void*)(p))

// ---------------------------------------------------------------------------
// K0: pred/gt (B,N,C,H,W) fp32 -> staged bf16 layout. One block per slab
// (one (b,n) pair = 16 rows x 256 c, 16 KB contiguous input). Also zeroes
// d_out (stream order guarantees this precedes combine's atomics).
// ---------------------------------------------------------------------------
__global__ __launch_bounds__(256) void transpose_stage(
    const float* __restrict__ pred, const float* __restrict__ gt,
    unsigned short* __restrict__ Xs, unsigned short* __restrict__ Ys,
    float* __restrict__ out) {
  int blk = blockIdx.x;
  if (blk == 0 && threadIdx.x == 0) { out[0] = 0.f; out[1] = 0.f; }
  const float* src;
  unsigned short* dst;
  int slab;
  if (blk < 256) { src = pred; dst = Xs; slab = blk; }
  else           { src = gt;   dst = Ys; slab = blk - 256; }
  const float* sb = src + slab * 4096;
  const int rb = slab >> 3, rowhi = slab & 7;
  const int t = threadIdx.x;
  #pragma unroll
  for (int half = 0; half < 2; ++half) {
    int c_ = half * 256 + t;                 // chunk id within slab, 0..511
    int rowlo = c_ & 15;
    int quad  = (c_ >> 4) & 3;
    int kk    = (c_ >> 6) & 1;
    int s     = c_ >> 7;
    int k0 = s * 64 + kk * 32 + quad * 8;
    unsigned int packed[4];
    #pragma unroll
    for (int jj = 0; jj < 4; ++jj) {
      unsigned int lohi[2];
      #pragma unroll
      for (int e = 0; e < 2; ++e) {
        float f = sb[(k0 + jj * 2 + e) * 16 + rowlo];
        unsigned int u = __float_as_uint(f);
        lohi[e] = (u + 0x7FFFu + ((u >> 16) & 1u)) >> 16;   // RNE -> bf16
      }
      packed[jj] = lohi[0] | (lohi[1] << 16);
    }
    unsigned short* o = dst + rb * 32768 +
        (unsigned)(s * 1024 + kk * 512 + rowhi * 64 + quad * 16 + rowlo) * 8;
    uint4 v; v.x = packed[0]; v.y = packed[1]; v.z = packed[2]; v.w = packed[3];
    *reinterpret_cast<uint4*>(o) = v;
  }
}

// ---------------------------------------------------------------------------
// K1: lossmat tile (128x128) = X @ Y^T, mfma_f32_16x16x32_bf16.
// 4 waves as 2x2 (rg,cg), wave tile 64x64 = 4x4 fragments.
// K streamed in 4 slabs of 64 through 32 KB LDS via global_load_lds(16B).
// Fused epilogue: per-row (max, sum-exp) partials per 64-col group (stored
// TRANSPOSED: [g][row] for coalesced combine); diagonal blocks write
// lossmat[i,i].
// ---------------------------------------------------------------------------
__global__ __launch_bounds__(256) void gemm_softmax_partial(
    const unsigned short* __restrict__ Xs, const unsigned short* __restrict__ Ys,
    float* __restrict__ pmax, float* __restrict__ psum, float* __restrict__ diag) {
  __shared__ __align__(16) unsigned short As[8192];  // 16 KB: 128 rows x 64 k
  __shared__ __align__(16) unsigned short Bs[8192];
  const int t = threadIdx.x;
  const int wave = t >> 6, lane = t & 63;
  const int rg = wave >> 1, cg = wave & 1;
  const int bR = blockIdx.x, bC = blockIdx.y;
  const unsigned short* Ag = Xs + bR * 32768;
  const unsigned short* Bg = Ys + bC * 32768;

  floatx4 acc[4][4];
  const floatx4 zero = {0.f, 0.f, 0.f, 0.f};
  #pragma unroll
  for (int i = 0; i < 4; ++i)
    #pragma unroll
    for (int j = 0; j < 4; ++j) acc[i][j] = zero;

  for (int s = 0; s < 4; ++s) {
    #pragma unroll
    for (int it = 0; it < 4; ++it) {
      int chunk = it * 256 + t;        // lane-linear: 16B per thread
      __builtin_amdgcn_global_load_lds(AS1C(Ag + s * 8192 + chunk * 8),
                                       AS3(As + chunk * 8), 16, 0, 0);
      __builtin_amdgcn_global_load_lds(AS1C(Bg + s * 8192 + chunk * 8),
                                       AS3(Bs + chunk * 8), 16, 0, 0);
    }
    __syncthreads();
    #pragma unroll
    for (int kk = 0; kk < 2; ++kk) {
      bf16x8 a[4], b[4];
      #pragma unroll
      for (int fr = 0; fr < 4; ++fr)
        a[fr] = *reinterpret_cast<const bf16x8*>(
            As + (unsigned)(kk * 512 + (rg * 4 + fr) * 64 + lane) * 8);
      #pragma unroll
      for (int fc = 0; fc < 4; ++fc)
        b[fc] = *reinterpret_cast<const bf16x8*>(
            Bs + (unsigned)(kk * 512 + (cg * 4 + fc) * 64 + lane) * 8);
      #pragma unroll
      for (int fr = 0; fr < 4; ++fr)
        #pragma unroll
        for (int fc = 0; fc < 4; ++fc)
          acc[fr][fc] = __builtin_amdgcn_mfma_f32_16x16x32_bf16(
              a[fr], b[fc], acc[fr][fc], 0, 0, 0);
    }
    if (s < 3) __syncthreads();
  }

  const int quad = lane >> 4, lc = lane & 15;

  // Diagonal extraction: row_local = fr*16+quad*4+reg, col_local = fc*16+lc.
  if (bR == bC && rg == cg) {
    #pragma unroll
    for (int fr = 0; fr < 4; ++fr)
      #pragma unroll
      for (int r = 0; r < 4; ++r)
        if (lc == quad * 4 + r)
          diag[bR * 128 + rg * 64 + fr * 16 + lc] = acc[fr][fr][r];
  }

  // Per-row partials over this wave's 64 cols. Each (fr,r) pair: 4 quads hold
  // 4 distinct rows; reduce across the 16 lc lanes (xor 1,2,4,8 stays in quad).
  const int g = bC * 2 + cg;             // col-group id, 0..63
  #pragma unroll
  for (int fr = 0; fr < 4; ++fr) {
    #pragma unroll
    for (int r = 0; r < 4; ++r) {
      float v0 = acc[fr][0][r], v1 = acc[fr][1][r];
      float v2 = acc[fr][2][r], v3 = acc[fr][3][r];
      float m = fmaxf(fmaxf(v0, v1), fmaxf(v2, v3));
      #pragma unroll
      for (int sh = 1; sh < 16; sh <<= 1) m = fmaxf(m, __shfl_xor(m, sh, 64));
      float ss = __expf(v0 - m) + __expf(v1 - m) +
                 __expf(v2 - m) + __expf(v3 - m);
      #pragma unroll
      for (int sh = 1; sh < 16; sh <<= 1) ss += __shfl_xor(ss, sh, 64);
      if (lc == 0) {
        int grow = bR * 128 + rg * 64 + fr * 16 + quad * 4 + r;
        int p = g * 4096 + grow;         // transposed: [g][row]
        pmax[p] = m; psum[p] = ss;
      }
    }
  }
}

// ---------------------------------------------------------------------------
// K2: per-row combine of 64 col-group partials -> loss/correct, wave-reduce,
// atomicAdd scaled partials into d_out (zeroed by K0).
// correct = (diag == global row max): argmax value IS the max; exact-fp tie
// with a non-diagonal column has measure zero.
// Layout [g][row] => lane-contiguous coalesced loads.
// ---------------------------------------------------------------------------
__global__ __launch_bounds__(64) void combine_rows(
    const float* __restrict__ pmax, const float* __restrict__ psum,
    const float* __restrict__ diag, float* __restrict__ out) {
  int row = blockIdx.x * 64 + threadIdx.x;
  float M = -3.4e38f;
  #pragma unroll 8
  for (int b = 0; b < 64; ++b) M = fmaxf(M, pmax[b * 4096 + row]);
  float S = 0.f;
  #pragma unroll 8
  for (int b = 0; b < 64; ++b)
    S += psum[b * 4096 + row] * __expf(pmax[b * 4096 + row] - M);
  float d = diag[row];
  float lossr = logf(S) + M - d;
  float corr = (d == M) ? 1.f : 0.f;
  #pragma unroll
  for (int sh = 1; sh < 64; sh <<= 1) {
    lossr += __shfl_xor(lossr, sh, 64);
    corr  += __shfl_xor(corr,  sh, 64);
  }
  if (threadIdx.x == 0) {
    atomicAdd(out + 0, lossr * (1.f / 4096.f));
    atomicAdd(out + 1, corr * (100.f / 4096.f));
  }
}

extern "C" void kernel_launch(void* const* d_in, const int* in_sizes, int n_in,
                              void* d_out, int out_size, void* d_ws, size_t ws_size,
                              hipStream_t stream) {
  const float* pred = (const float*)d_in[0];
  const float* gt   = (const float*)d_in[1];
  char* w = (char*)d_ws;
  unsigned short* Xbf = (unsigned short*)(w + OFF_X);
  unsigned short* Ybf = (unsigned short*)(w + OFF_Y);
  float* pmax  = (float*)(w + OFF_PMAX);
  float* psum  = (float*)(w + OFF_PSUM);
  float* diag  = (float*)(w + OFF_DIAG);
  float* out   = (float*)d_out;

  transpose_stage<<<512, 256, 0, stream>>>(pred, gt, Xbf, Ybf, out);
  dim3 g1(32, 32);
  gemm_softmax_partial<<<g1, 256, 0, stream>>>(Xbf, Ybf, pmax, psum, diag);
  combine_rows<<<64, 64, 0, stream>>>(pmax, psum, diag, out);
}